// Round 9
// baseline (390.882 us; speedup 1.0000x reference)
//
#include <hip/hip_runtime.h>
#include <hip/hip_bf16.h>

// Problem constants (B,T,D,H,KV,HD,RD from reference)
static constexpr int B_  = 2;
static constexpr int T_  = 2048;
static constexpr int D_  = 2048;
static constexpr int H_  = 16;
static constexpr int KV_ = 4;
static constexpr int HD_ = 128;
static constexpr int RD_ = 64;
static constexpr int BT_ = B_ * T_;           // 4096
static constexpr int NPROJ_ = 3072;           // Q(2048) | K(512) | V(512) fused
static constexpr float SCALE_ = 0.08838834764831845f; // 1/sqrt(128)

typedef __attribute__((ext_vector_type(8))) short bf16x8;
typedef __attribute__((ext_vector_type(8))) unsigned short u16x8;
typedef __attribute__((ext_vector_type(4))) float f32x4;

#define COMPILER_BARRIER() __asm__ __volatile__("" ::: "memory")
#define BAR() do { COMPILER_BARRIER(); __builtin_amdgcn_s_barrier(); COMPILER_BARRIER(); } while (0)

// async global->LDS DMA, 16B per lane; LDS dest = wave-uniform base + lane*16
typedef const __attribute__((address_space(1))) unsigned int* as1_u32p;
typedef __attribute__((address_space(3))) unsigned int* as3_u32p;
#define GLOAD16(g, l) __builtin_amdgcn_global_load_lds((as1_u32p)(const void*)(g), (as3_u32p)(void*)(l), 16, 0, 0)

// f32 -> bf16 (RNE) raw bits
__device__ __forceinline__ unsigned short f2bu(float f) {
  unsigned x = __float_as_uint(f);
  unsigned r = (x + 0x7fffu + ((x >> 16) & 1u)) >> 16;
  return (unsigned short)r;
}

// ---------------- f32 -> bf16 elementwise (n divisible by 1024) ----------------
__global__ __launch_bounds__(256) void cvt_bf16(const float* __restrict__ in,
                                                unsigned short* __restrict__ out) {
  const size_t i = ((size_t)blockIdx.x * 256 + threadIdx.x) * 4;
  const float4 f = *(const float4*)(in + i);
  ushort4 o;
  o.x = f2bu(f.x); o.y = f2bu(f.y); o.z = f2bu(f.z); o.w = f2bu(f.w);
  *(ushort4*)(out + i) = o;
}

// ---------------- all 4 weight transposes in ONE launch: f32 [R,C] -> bf16 [C,R] ----------------
__global__ __launch_bounds__(256) void t32_all(const float* __restrict__ Wq,
                                               const float* __restrict__ Wk,
                                               const float* __restrict__ Wv,
                                               const float* __restrict__ Wo,
                                               unsigned short* __restrict__ Wqt,
                                               unsigned short* __restrict__ Wkvt,
                                               unsigned short* __restrict__ Wot) {
  const float* in; unsigned short* out; int C;
  switch (blockIdx.z) {
    case 0:  in = Wq; out = Wqt;                       C = 2048; break;
    case 1:  in = Wk; out = Wkvt;                      C = 512;  break;
    case 2:  in = Wv; out = Wkvt + (size_t)512 * D_;   C = 512;  break;
    default: in = Wo; out = Wot;                       C = 2048; break;
  }
  if ((int)blockIdx.y * 32 >= C) return;   // Wk/Wv only span 16 y-blocks

  __shared__ unsigned short tile[32][36];
  const int r0 = blockIdx.x * 32;
  const int c0 = blockIdx.y * 32;
  const int tid = threadIdx.x;
  {
    const int r = tid >> 3;
    const int c = (tid & 7) * 4;
    const float4 f = *(const float4*)(in + (size_t)(r0 + r) * C + c0 + c);
    ushort4 w;
    w.x = f2bu(f.x); w.y = f2bu(f.y); w.z = f2bu(f.z); w.w = f2bu(f.w);
    *(ushort4*)&tile[r][c] = w;
  }
  __syncthreads();
  {
    const int c = tid >> 3;
    const int r = (tid & 7) * 4;
    ushort4 o;
    o.x = tile[r + 0][c];
    o.y = tile[r + 1][c];
    o.z = tile[r + 2][c];
    o.w = tile[r + 3][c];
    *(ushort4*)(out + (size_t)(c0 + c) * D_ + r0 + r) = o;
  }
}

// ---------------- 256x256 8-phase bf16 GEMM (T2 swizzle + T3/T4 counted vmcnt + T5) ----------------
// 8 waves (2Mx4N), BK=64, LDS 128 KiB dbuf, linear gload_lds dest + pre-swizzled global
// source, per-phase vmcnt(6), peeled drain 4->2->0.
// Trailing BAR() per K-tile closes all waves' ds_reads of buffer b before the next
// iteration's p0 issues DMA into b (WAR window; m201 template carries this barrier).
template <int EPI>
__global__ __launch_bounds__(512, 1) void gemm256(const unsigned short* __restrict__ A,
                                                  const unsigned short* __restrict__ Bt,
                                                  float* __restrict__ C,
                                                  unsigned short* __restrict__ Qbf,
                                                  float* __restrict__ kout,
                                                  float* __restrict__ vout,
                                                  unsigned short* __restrict__ Kbf,
                                                  const float* __restrict__ cosb,
                                                  const float* __restrict__ sinb,
                                                  int N) {
  __shared__ __align__(16) unsigned short As[2][256 * 64];
  __shared__ __align__(16) unsigned short Bs[2][256 * 64];
  constexpr int K = D_;          // 2048
  constexpr int KT = K / 64;     // 32

  const int tid = threadIdx.x;
  const int lane = tid & 63;
  const int wave = tid >> 6;
  const int n16 = lane & 15;
  const int quad = lane >> 4;
  const int wm = wave >> 2;      // 0..1
  const int wn = wave & 3;       // 0..3

  // XCD-aware bijective swizzle (both grids have nwg % 8 == 0)
  const int nwg = gridDim.x * gridDim.y;
  int bid = blockIdx.y * gridDim.x + blockIdx.x;
  bid = (bid & 7) * (nwg >> 3) + (bid >> 3);
  const int bn = (bid % (int)gridDim.x) * 256;
  const int bm = (bid / (int)gridDim.x) * 256;

  const int t8 = tid >> 3;
  const int kg = ((tid & 7) ^ (t8 & 7)) << 3;
  const unsigned short *aS0[2], *aS1[2], *bS0[2], *bS1[2];
#pragma unroll
  for (int g = 0; g < 2; ++g) {
    aS0[g] = A + (size_t)(bm + g * 128 + t8) * K + kg;
    aS1[g] = A + (size_t)(bm + g * 128 + 64 + t8) * K + kg;
    const int br = (g * 2 + (t8 >> 5)) * 64 + (t8 & 31);
    bS0[g] = Bt + (size_t)(bn + br) * K + kg;
    bS1[g] = Bt + (size_t)(bn + br + 32) * K + kg;
  }

#define STAGE(dst, half, src, koff)                                             \
  do {                                                                          \
    GLOAD16((src)[0] + (koff), &(dst)[((half) * 128 + 0) * 64 + wave * 512]);   \
    GLOAD16((src)[1] + (koff), &(dst)[((half) * 128 + 64) * 64 + wave * 512]);  \
  } while (0)

#define LDA(MH)                                                                   \
  _Pragma("unroll") for (int ks = 0; ks < 2; ++ks)                                \
  _Pragma("unroll") for (int i = 0; i < 4; ++i)                                   \
      aF[ks][i] = *(const bf16x8*)&cA[((MH) * 128 + wm * 64 + i * 16 + n16) * 64  \
                                      + ((quad * 8 + ks * 32) ^ ((n16 & 7) << 3))];

#define LDB(DST, NH)                                                              \
  _Pragma("unroll") for (int ks = 0; ks < 2; ++ks)                                \
  _Pragma("unroll") for (int jj = 0; jj < 2; ++jj)                                \
      DST[ks][jj] = *(const bf16x8*)&cB[((NH) * 128 + wn * 32 + jj * 16 + n16) * 64 \
                                        + ((quad * 8 + ks * 32) ^ ((n16 & 7) << 3))];

#define MFQ(MH, NH, BF)                                                           \
  do {                                                                            \
    __builtin_amdgcn_s_setprio(1);                                                \
    _Pragma("unroll") for (int ks = 0; ks < 2; ++ks)                              \
    _Pragma("unroll") for (int i = 0; i < 4; ++i)                                 \
    _Pragma("unroll") for (int jj = 0; jj < 2; ++jj)                              \
        acc[(MH) * 4 + i][(NH) * 2 + jj] = __builtin_amdgcn_mfma_f32_16x16x32_bf16( \
            aF[ks][i], BF[ks][jj], acc[(MH) * 4 + i][(NH) * 2 + jj], 0, 0, 0);    \
    __builtin_amdgcn_s_setprio(0);                                                \
  } while (0)

  f32x4 acc[8][4];
#pragma unroll
  for (int mi = 0; mi < 8; ++mi)
#pragma unroll
    for (int ni = 0; ni < 4; ++ni) acc[mi][ni] = (f32x4){0.f, 0.f, 0.f, 0.f};

  bf16x8 aF[2][4], b0F[2][2], b1F[2][2];

  // prologue: tile 0 in need order HA0, HB0, HB1, HA1 (8 loads outstanding)
  STAGE(As[0], 0, aS0, 0);
  STAGE(Bs[0], 0, bS0, 0);
  STAGE(Bs[0], 1, bS1, 0);
  STAGE(As[0], 1, aS1, 0);

  for (int kt = 0; kt < KT - 1; ++kt) {
    const unsigned short* cA = As[kt & 1];
    const unsigned short* cB = Bs[kt & 1];
    unsigned short* nA = As[(kt & 1) ^ 1];
    unsigned short* nB = Bs[(kt & 1) ^ 1];
    const int ko = (kt + 1) * 64;

    // p0: needs HA0(t),HB0(t) (3 younger halves in flight -> vmcnt(6))
    STAGE(nA, 0, aS0, ko);
    asm volatile("s_waitcnt vmcnt(6)" ::: "memory");
    BAR();
    LDA(0); LDB(b0F, 0);
    MFQ(0, 0, b0F);
    // p1: needs HB1(t)
    STAGE(nB, 0, bS0, ko);
    asm volatile("s_waitcnt vmcnt(6)" ::: "memory");
    BAR();
    LDB(b1F, 1);
    MFQ(0, 1, b1F);
    // p2: needs HA1(t)
    STAGE(nB, 1, bS1, ko);
    asm volatile("s_waitcnt vmcnt(6)" ::: "memory");
    BAR();
    LDA(1);
    MFQ(1, 0, b0F);
    // p3: pure compute (all frags in regs)
    STAGE(nA, 1, aS1, ko);
    MFQ(1, 1, b1F);
    BAR();   // close this tile's ds_reads before next p0 DMAs into this buffer
  }

  // peeled last tile: nothing more to issue; drain 4 -> 2 -> 0
  {
    const unsigned short* cA = As[(KT - 1) & 1];
    const unsigned short* cB = Bs[(KT - 1) & 1];
    asm volatile("s_waitcnt vmcnt(4)" ::: "memory");
    BAR();
    LDA(0); LDB(b0F, 0);
    MFQ(0, 0, b0F);
    asm volatile("s_waitcnt vmcnt(2)" ::: "memory");
    BAR();
    LDB(b1F, 1);
    MFQ(0, 1, b1F);
    asm volatile("s_waitcnt vmcnt(0)" ::: "memory");
    BAR();
    LDA(1);
    MFQ(1, 0, b0F);
    MFQ(1, 1, b1F);
  }

  // ---- epilogue ----
#pragma unroll
  for (int mi = 0; mi < 8; ++mi) {
#pragma unroll
    for (int rr = 0; rr < 4; ++rr) {
      const int row = bm + wm * 128 + mi * 16 + quad * 4 + rr;
      if (EPI == 0) {
#pragma unroll
        for (int ni = 0; ni < 4; ++ni) {
          const int col = bn + wn * 64 + ni * 16 + n16;
          C[(size_t)row * N + col] = acc[mi][ni][rr];
        }
      } else {
        const int b = row >> 11, t = row & (T_ - 1);
#pragma unroll
        for (int ni = 0; ni < 4; ++ni) {
          const int col = bn + wn * 64 + ni * 16 + n16;
          const int hd = col & 127;
          float v = acc[mi][ni][rr];
          const float other = __shfl_xor(v, 1);   // RoPE pair (col^1), all lanes execute
          if (col < 2560 && hd < RD_) {
            const float c = cosb[t * 32 + (hd >> 1)];
            const float s = sinb[t * 32 + (hd >> 1)];
            v = (col & 1) ? (other * s + v * c) : (v * c - other * s);
          }
          if (col < 2048) {
            Qbf[(size_t)row * (H_ * HD_) + col] = f2bu(v * SCALE_);
          } else if (col < 2560) {
            const int kv = (col - 2048) >> 7;
            const size_t idx = (((size_t)(b * KV_ + kv) * T_) + t) * HD_ + hd;
            kout[idx] = v;
            Kbf[idx] = f2bu(v);
          } else {
            const int kv = (col - 2560) >> 7;
            vout[(((size_t)(b * KV_ + kv) * T_) + t) * HD_ + hd] = v;
          }
        }
      }
    }
  }
#undef STAGE
#undef LDA
#undef LDB
#undef MFQ
}

// ---------------- V transpose: vout f32 [G,T,HD] -> VbfT bf16 [G,HD,T], pi-permuted ----------------
// Keys within each 32-key chunk stored in the MFMA A-frag contraction order of the attention
// P fragment: 4 consecutive source keys kc..kc+3 land at slot base ((kc&15)<<1)|((kc&16)>>2).
__global__ __launch_bounds__(256) void v_transpose(const float* __restrict__ vin,
                                                   unsigned short* __restrict__ vt) {
  __shared__ unsigned int tile[32][17];
  const int tid = threadIdx.x;
  const int k0 = blockIdx.x * 32;
  const int d0 = blockIdx.y * 32;
  const int g  = blockIdx.z;
  const float* src = vin + ((size_t)g * T_ + k0) * HD_ + d0;

  {
    const int kr = tid >> 3;
    const int d2 = (tid & 7) * 2;
#pragma unroll
    for (int c = 0; c < 2; ++c) {
      const float2 f = *(const float2*)(src + (size_t)kr * HD_ + (d2 + c) * 2);
      tile[kr][d2 + c] = (unsigned)f2bu(f.x) | ((unsigned)f2bu(f.y) << 16);
    }
  }
  __syncthreads();
  {
    const int dr = tid >> 3;
    const int kc = (tid & 7) * 4;
    const int dstb = ((kc & 15) << 1) | ((kc & 16) >> 2);
    const int hi = dr >> 1;
    const int sh = (dr & 1) * 16;
    ushort4 o;
    o.x = (unsigned short)(tile[kc + 0][hi] >> sh);
    o.y = (unsigned short)(tile[kc + 1][hi] >> sh);
    o.z = (unsigned short)(tile[kc + 2][hi] >> sh);
    o.w = (unsigned short)(tile[kc + 3][hi] >> sh);
    *(ushort4*)(vt + ((size_t)g * HD_ + d0 + dr) * T_ + k0 + dstb) = o;
  }
}

// ---------------- flash attention v5 (reverted from split-K): paired q-tiles, swapped QK^T ----------------
// Block = (pair pid, b, kvh): tile A = qt pid, tile B = qt 127-pid -> equal work per block.
// Q is pre-rope'd, pre-scaled bf16 (from gemm256<1>) -> frag load is a single b128 per slice.
// Alpha / l broadcasts via __shfl (wave-uniform branches) instead of LDS round-trips.
// (Split-K v6/v6b NaN'd twice; reverted pending root cause. This version passed at 103.8 us.)
__global__ __launch_bounds__(256, 2) void attn_flash(const unsigned short* __restrict__ Q,
                                                     const unsigned short* __restrict__ Kbf,
                                                     const unsigned short* __restrict__ VbfT,
                                                     unsigned short* __restrict__ O) {
  __shared__ __align__(16) unsigned short Ks[32 * 128];  // [key][d], swizzled
  __shared__ __align__(16) unsigned short Vs[128 * 32];  // [d][key-slot], swizzled

  const int tid = threadIdx.x;
  const int wave = tid >> 6;        // = head within kv group
  const int lane = tid & 63;
  const int n16 = lane & 15;
  const int quad = lane >> 4;
  const int pid = blockIdx.x;       // 0..63
  const int q0A = pid * 16;
  const int q0B = (127 - pid) * 16;
  const int nchA = (q0A + 47) >> 5;
  const int nchB = (q0B + 47) >> 5;
  const int bkv = blockIdx.y;
  const int b = bkv >> 2;
  const int kvh = bkv & 3;
  const int h = kvh * 4 + wave;

  const unsigned short* ksrc = Kbf + ((size_t)(b * KV_ + kvh)) * T_ * HD_;
  const unsigned short* vtsrc = VbfT + ((size_t)(b * KV_ + kvh)) * HD_ * T_;

  const int krow = tid >> 4;            // 0..15 (+16 for second op)
  const int kcol = (tid & 15) * 8;
  const int kdst0 = (krow * 128 + kcol) ^ ((krow & 7) << 3);
  const int kdst1 = ((krow + 16) * 128 + kcol) ^ ((krow & 7) << 3);
  const int vrow = tid >> 2;            // 0..63 (+64 for second op)
  const int vcol = (tid & 3) * 8;
  const int vdst0 = (vrow * 32 + vcol) ^ ((vrow & 3) << 3);
  const int vdst1 = ((vrow + 64) * 32 + vcol) ^ ((vrow & 3) << 3);

  // Q A-frags (bf16, rope'd, pre-scaled); lane n16 owns q-row q0+n16
  bf16x8 qfA[4], qfB[4];
  {
    const unsigned short* qa = Q + ((size_t)(b * T_ + q0A + n16)) * (H_ * HD_) + h * HD_ + quad * 8;
    const unsigned short* qb = Q + ((size_t)(b * T_ + q0B + n16)) * (H_ * HD_) + h * HD_ + quad * 8;
#pragma unroll
    for (int s = 0; s < 4; ++s) {
      qfA[s] = *(const bf16x8*)(qa + s * 32);
      qfB[s] = *(const bf16x8*)(qb + s * 32);
    }
  }

  float mA = -1e30f, lA = 0.f;
  float mB = -1e30f, lB = 0.f;
  f32x4 oA[8], oB[8];
#pragma unroll
  for (int t = 0; t < 8; ++t) { oA[t] = (f32x4){0.f,0.f,0.f,0.f}; oB[t] = (f32x4){0.f,0.f,0.f,0.f}; }

  // stage chunk 0
  {
    const u16x8 ka = *(const u16x8*)(ksrc + (size_t)krow * HD_ + kcol);
    const u16x8 kb = *(const u16x8*)(ksrc + (size_t)(krow + 16) * HD_ + kcol);
    const u16x8 va = *(const u16x8*)(vtsrc + (size_t)vrow * T_ + vcol);
    const u16x8 vb = *(const u16x8*)(vtsrc + (size_t)(vrow + 64) * T_ + vcol);
    *(u16x8*)&Ks[kdst0] = ka;
    *(u16x8*)&Ks[kdst1] = kb;
    *(u16x8*)&Vs[vdst0] = va;
    *(u16x8*)&Vs[vdst1] = vb;
  }
  __syncthreads();

  for (int c = 0; c < nchB; ++c) {
    const int kc = c * 32;
    const bool actA = (c < nchA);

    // prefetch next chunk to regs; LDS writes happen after the post-compute barrier
    u16x8 ka, kb, va, vb;
    if (c + 1 < nchB) {
      ka = *(const u16x8*)(ksrc + (size_t)(kc + 32 + krow) * HD_ + kcol);
      kb = *(const u16x8*)(ksrc + (size_t)(kc + 48 + krow) * HD_ + kcol);
      va = *(const u16x8*)(vtsrc + (size_t)vrow * T_ + (kc + 32) + vcol);
      vb = *(const u16x8*)(vtsrc + (size_t)(vrow + 64) * T_ + (kc + 32) + vcol);
    }
    COMPILER_BARRIER();

    // ---- swapped QK^T, K-frags shared by both tiles ----
    f32x4 sB0 = (f32x4){0.f,0.f,0.f,0.f}, sB1 = sB0, sA0 = sB0, sA1 = sB0;
#pragma unroll
    for (int s = 0; s < 4; ++s) {
      const bf16x8 kf0 = *(const bf16x8*)&Ks[(n16 * 128 + quad * 8 + s * 32) ^ ((n16 & 7) << 3)];
      const bf16x8 kf1 = *(const bf16x8*)&Ks[((16 + n16) * 128 + quad * 8 + s * 32) ^ ((n16 & 7) << 3)];
      sB0 = __builtin_amdgcn_mfma_f32_16x16x32_bf16(kf0, qfB[s], sB0, 0, 0, 0);
      sB1 = __builtin_amdgcn_mfma_f32_16x16x32_bf16(kf1, qfB[s], sB1, 0, 0, 0);
      if (actA) {
        sA0 = __builtin_amdgcn_mfma_f32_16x16x32_bf16(kf0, qfA[s], sA0, 0, 0, 0);
        sA1 = __builtin_amdgcn_mfma_f32_16x16x32_bf16(kf1, qfA[s], sA1, 0, 0, 0);
      }
    }

    // ---- softmax B (lane-local row q0B+n16; s[] already in A-frag slot order) ----
    union { bf16x8 v; unsigned short u[8]; } pkB, pkA;
    bool growB;
    float alphaB = 1.f, alphaA = 1.f;
    {
      float s[8];
#pragma unroll
      for (int r = 0; r < 4; ++r) { s[r] = sB0[r]; s[r + 4] = sB1[r]; }
      if (c == nchB - 1) {
        const int qrow = q0B + n16;
#pragma unroll
        for (int r = 0; r < 4; ++r) {
          if (kc + quad * 4 + r > qrow)      s[r]     = -1e30f;
          if (kc + 16 + quad * 4 + r > qrow) s[r + 4] = -1e30f;
        }
      }
      float mm = fmaxf(fmaxf(fmaxf(s[0], s[1]), fmaxf(s[2], s[3])),
                       fmaxf(fmaxf(s[4], s[5]), fmaxf(s[6], s[7])));
      mm = fmaxf(mm, __shfl_xor(mm, 16));
      mm = fmaxf(mm, __shfl_xor(mm, 32));
      growB = __any(mm > mB);
      if (growB) {
        const float mnew = fmaxf(mB, mm);
        alphaB = __expf(mB - mnew);
        mB = mnew;
      }
      float lsum = 0.f;
#pragma unroll
      for (int j = 0; j < 8; ++j) {
        const float p = __expf(s[j] - mB);
        lsum += p;
        pkB.u[j] = f2bu(p);
      }
      lsum += __shfl_xor(lsum, 16);
      lsum += __shfl_xor(lsum, 32);
      lB = growB ? (alphaB * lB + lsum) : (lB + lsum);
    }

    // ---- softmax A ----
    bool growA = false;
    if (actA) {
      float s[8];
#pragma unroll
      for (int r = 0; r < 4; ++r) { s[r] = sA0[r]; s[r + 4] = sA1[r]; }
      if (c == nchA - 1) {
        const int qrow = q0A + n16;
#pragma unroll
        for (int r = 0; r < 4; ++r) {
          if (kc + quad * 4 + r > qrow)      s[r]     = -1e30f;
          if (kc + 16 + quad * 4 + r > qrow) s[r + 4] = -1e30f;
        }
      }
      float mm = fmaxf(fmaxf(fmaxf(s[0], s[1]), fmaxf(s[2], s[3])),
                       fmaxf(fmaxf(s[4], s[5]), fmaxf(s[6], s[7])));
      mm = fmaxf(mm, __shfl_xor(mm, 16));
      mm = fmaxf(mm, __shfl_xor(mm, 32));
      growA = __any(mm > mA);
      if (growA) {
        const float mnew = fmaxf(mA, mm);
        alphaA = __expf(mA - mnew);
        mA = mnew;
      }
      float lsum = 0.f;
#pragma unroll
      for (int j = 0; j < 8; ++j) {
        const float p = __expf(s[j] - mA);
        lsum += p;
        pkA.u[j] = f2bu(p);
      }
      lsum += __shfl_xor(lsum, 16);
      lsum += __shfl_xor(lsum, 32);
      lA = growA ? (alphaA * lA + lsum) : (lA + lsum);
    }

    // ---- O rescale only when max grew; alpha broadcast row->C-layout via shfl ----
    if (growB) {
      f32x4 av;
#pragma unroll
      for (int r = 0; r < 4; ++r) av[r] = __shfl(alphaB, quad * 4 + r);
#pragma unroll
      for (int t = 0; t < 8; ++t) {
        oB[t][0] *= av[0]; oB[t][1] *= av[1]; oB[t][2] *= av[2]; oB[t][3] *= av[3];
      }
    }
    if (growA) {
      f32x4 av;
#pragma unroll
      for (int r = 0; r < 4; ++r) av[r] = __shfl(alphaA, quad * 4 + r);
#pragma unroll
      for (int t = 0; t < 8; ++t) {
        oA[t][0] *= av[0]; oA[t][1] *= av[1]; oA[t][2] *= av[2]; oA[t][3] *= av[3];
      }
    }

    // ---- PV, V-frags shared by both tiles (pi-permuted layout matches pk order) ----
#pragma unroll
    for (int t = 0; t < 8; ++t) {
      const bf16x8 vf = *(const bf16x8*)&Vs[((t * 16 + n16) * 32 + quad * 8) ^ ((n16 & 3) << 3)];
      oB[t] = __builtin_amdgcn_mfma_f32_16x16x32_bf16(pkB.v, vf, oB[t], 0, 0, 0);
      if (actA) oA[t] = __builtin_amdgcn_mfma_f32_16x16x32_bf16(pkA.v, vf, oA[t], 0, 0, 0);
    }

    __syncthreads();      // all waves done reading this chunk's K/V tiles
    if (c + 1 < nchB) {
      *(u16x8*)&Ks[kdst0] = ka;
      *(u16x8*)&Ks[kdst1] = kb;
      *(u16x8*)&Vs[vdst0] = va;
      *(u16x8*)&Vs[vdst1] = vb;
    }
    __syncthreads();      // next chunk's tiles visible to all waves
  }

  // ---- epilogue: normalize (l via shfl), store bf16 (both tiles) ----
  {
    unsigned short* obB = O + ((size_t)(b * T_ + q0B)) * (H_ * HD_) + h * HD_;
    unsigned short* obA = O + ((size_t)(b * T_ + q0A)) * (H_ * HD_) + h * HD_;
#pragma unroll
    for (int r = 0; r < 4; ++r) {
      const float liB = 1.0f / __shfl(lB, quad * 4 + r);
      const float liA = 1.0f / __shfl(lA, quad * 4 + r);
#pragma unroll
      for (int t = 0; t < 8; ++t) {
        obB[(size_t)(quad * 4 + r) * (H_ * HD_) + t * 16 + n16] = f2bu(oB[t][r] * liB);
        obA[(size_t)(quad * 4 + r) * (H_ * HD_) + t * 16 + n16] = f2bu(oA[t][r] * liA);
      }
    }
  }
}

extern "C" void kernel_launch(void* const* d_in, const int* in_sizes, int n_in,
                              void* d_out, int out_size, void* d_ws, size_t ws_size,
                              hipStream_t stream) {
  const float* x  = (const float*)d_in[0];
  const float* fc = (const float*)d_in[1];
  const float* fs = (const float*)d_in[2];
  const float* Wq = (const float*)d_in[3];
  const float* Wk = (const float*)d_in[4];
  const float* Wv = (const float*)d_in[5];
  const float* Wo = (const float*)d_in[6];

  // Outputs (f32), concatenated: y | present_k | present_v
  float* yout = (float*)d_out;                          // [B,T,D]
  float* kout = yout + (size_t)B_ * T_ * D_;            // [B,KV,T,HD]
  float* vout = kout + (size_t)B_ * KV_ * T_ * HD_;     // [B,KV,T,HD]
  unsigned short* Qbf = (unsigned short*)yout;          // bf16 Q staging in yout region

  // workspace (bf16, 44 MB): xb/Abf (aliased) | Wqt | Wkvt | Wot | Kbf | VbfT
  unsigned short* xb   = (unsigned short*)d_ws;                    // [BT, D]
  unsigned short* Abf  = xb;                                       // alias: xb dead after gemm256<1>
  unsigned short* Wqt  = xb   + (size_t)BT_ * D_;                  // [2048, 2048]
  unsigned short* Wkvt = Wqt  + (size_t)D_ * D_;                   // [1024, 2048] (contiguous after Wqt)
  unsigned short* Wot  = Wkvt + (size_t)1024 * D_;                 // [2048, 2048]
  unsigned short* Kbf  = Wot  + (size_t)D_ * D_;                   // [B,KV,T,HD]
  unsigned short* VbfT = Kbf  + (size_t)B_ * KV_ * T_ * HD_;       // [B*KV, HD, T] (pi-permuted)

  dim3 blk(256);

  // input conversions
  cvt_bf16<<<dim3((BT_ * D_) / 1024), blk, 0, stream>>>(x, xb);
  t32_all<<<dim3(D_ / 32, D_ / 32, 4), blk, 0, stream>>>(Wq, Wk, Wv, Wo, Wqt, Wkvt, Wot);

  // fused QKV projection + RoPE (8-phase 256^2; Bt = Wqt||Wkvt contiguous)
  gemm256<1><<<dim3(NPROJ_ / 256, BT_ / 256), dim3(512), 0, stream>>>(
      xb, Wqt, nullptr, Qbf, kout, vout, Kbf, fc, fs, NPROJ_);

  // V^T bf16 mirror (pi-permuted)
  v_transpose<<<dim3(T_ / 32, HD_ / 32, B_ * KV_), blk, 0, stream>>>(vout, VbfT);

  // flash attention v5: 512 equal-work paired blocks, 4 waves each
  attn_flash<<<dim3(64, B_ * KV_), blk, 0, stream>>>(Qbf, Kbf, VbfT, Abf);

  // output projection (8-phase 256^2); overwrites Qbf staging with y
  gemm256<0><<<dim3(D_ / 256, BT_ / 256), dim3(512), 0, stream>>>(
      Abf, Wot, yout, nullptr, nullptr, nullptr, nullptr, nullptr, nullptr, D_);
}

// Round 10
// 386.176 us; speedup vs baseline: 1.0122x; 1.0122x over previous
//
#include <hip/hip_runtime.h>
#include <hip/hip_bf16.h>

// Problem constants (B,T,D,H,KV,HD,RD from reference)
static constexpr int B_  = 2;
static constexpr int T_  = 2048;
static constexpr int D_  = 2048;
static constexpr int H_  = 16;
static constexpr int KV_ = 4;
static constexpr int HD_ = 128;
static constexpr int RD_ = 64;
static constexpr int BT_ = B_ * T_;           // 4096
static constexpr int NPROJ_ = 3072;           // Q(2048) | K(512) | V(512) fused
static constexpr float SCALE_ = 0.08838834764831845f; // 1/sqrt(128)

typedef __attribute__((ext_vector_type(8))) short bf16x8;
typedef __attribute__((ext_vector_type(8))) unsigned short u16x8;
typedef __attribute__((ext_vector_type(4))) float f32x4;

#define COMPILER_BARRIER() __asm__ __volatile__("" ::: "memory")
#define BAR() do { COMPILER_BARRIER(); __builtin_amdgcn_s_barrier(); COMPILER_BARRIER(); } while (0)

// async global->LDS DMA, 16B per lane; LDS dest = wave-uniform base + lane*16
typedef const __attribute__((address_space(1))) unsigned int* as1_u32p;
typedef __attribute__((address_space(3))) unsigned int* as3_u32p;
#define GLOAD16(g, l) __builtin_amdgcn_global_load_lds((as1_u32p)(const void*)(g), (as3_u32p)(void*)(l), 16, 0, 0)

// f32 -> bf16 (RNE) raw bits
__device__ __forceinline__ unsigned short f2bu(float f) {
  unsigned x = __float_as_uint(f);
  unsigned r = (x + 0x7fffu + ((x >> 16) & 1u)) >> 16;
  return (unsigned short)r;
}

// ---------------- f32 -> bf16 elementwise (n divisible by 1024) ----------------
__global__ __launch_bounds__(256) void cvt_bf16(const float* __restrict__ in,
                                                unsigned short* __restrict__ out) {
  const size_t i = ((size_t)blockIdx.x * 256 + threadIdx.x) * 4;
  const float4 f = *(const float4*)(in + i);
  ushort4 o;
  o.x = f2bu(f.x); o.y = f2bu(f.y); o.z = f2bu(f.z); o.w = f2bu(f.w);
  *(ushort4*)(out + i) = o;
}

// ---------------- all 4 weight transposes in ONE launch: f32 [R,C] -> bf16 [C,R] ----------------
__global__ __launch_bounds__(256) void t32_all(const float* __restrict__ Wq,
                                               const float* __restrict__ Wk,
                                               const float* __restrict__ Wv,
                                               const float* __restrict__ Wo,
                                               unsigned short* __restrict__ Wqt,
                                               unsigned short* __restrict__ Wkvt,
                                               unsigned short* __restrict__ Wot) {
  const float* in; unsigned short* out; int C;
  switch (blockIdx.z) {
    case 0:  in = Wq; out = Wqt;                       C = 2048; break;
    case 1:  in = Wk; out = Wkvt;                      C = 512;  break;
    case 2:  in = Wv; out = Wkvt + (size_t)512 * D_;   C = 512;  break;
    default: in = Wo; out = Wot;                       C = 2048; break;
  }
  if ((int)blockIdx.y * 32 >= C) return;   // Wk/Wv only span 16 y-blocks

  __shared__ unsigned short tile[32][36];
  const int r0 = blockIdx.x * 32;
  const int c0 = blockIdx.y * 32;
  const int tid = threadIdx.x;
  {
    const int r = tid >> 3;
    const int c = (tid & 7) * 4;
    const float4 f = *(const float4*)(in + (size_t)(r0 + r) * C + c0 + c);
    ushort4 w;
    w.x = f2bu(f.x); w.y = f2bu(f.y); w.z = f2bu(f.z); w.w = f2bu(f.w);
    *(ushort4*)&tile[r][c] = w;
  }
  __syncthreads();
  {
    const int c = tid >> 3;
    const int r = (tid & 7) * 4;
    ushort4 o;
    o.x = tile[r + 0][c];
    o.y = tile[r + 1][c];
    o.z = tile[r + 2][c];
    o.w = tile[r + 3][c];
    *(ushort4*)(out + (size_t)(c0 + c) * D_ + r0 + r) = o;
  }
}

// ---------------- 256x256 bf16 GEMM: T2 swizzle + counted vmcnt + open scheduling region ----------------
// 8 waves (2Mx4N), BK=64, LDS 128 KiB dbuf, linear gload_lds dest + pre-swizzled global source.
// R10: 2 barriers per K-tile (was 4). Per tile: STAGE 8 gloads (tile t+1) -> vmcnt(8)
// (tile t's own 8 complete; per-wave wait + barrier => all waves' stages visible) -> BAR ->
// {24 ds_reads + 64 MFMAs, barrier-free: compiler interleaves DS and MFMA pipes; two A-frag
// arrays so quadrant(0,0) MFMAs hide half-1 A-loads} -> BAR (WAR: close reads before next
// iteration DMAs into this buffer). Peeled last tile drains vmcnt(0).
template <int EPI>
__global__ __launch_bounds__(512, 1) void gemm256(const unsigned short* __restrict__ A,
                                                  const unsigned short* __restrict__ Bt,
                                                  float* __restrict__ C,
                                                  unsigned short* __restrict__ Qbf,
                                                  float* __restrict__ kout,
                                                  float* __restrict__ vout,
                                                  unsigned short* __restrict__ Kbf,
                                                  const float* __restrict__ cosb,
                                                  const float* __restrict__ sinb,
                                                  int N) {
  __shared__ __align__(16) unsigned short As[2][256 * 64];
  __shared__ __align__(16) unsigned short Bs[2][256 * 64];
  constexpr int K = D_;          // 2048
  constexpr int KT = K / 64;     // 32

  const int tid = threadIdx.x;
  const int lane = tid & 63;
  const int wave = tid >> 6;
  const int n16 = lane & 15;
  const int quad = lane >> 4;
  const int wm = wave >> 2;      // 0..1
  const int wn = wave & 3;       // 0..3

  // XCD-aware bijective swizzle (both grids have nwg % 8 == 0)
  const int nwg = gridDim.x * gridDim.y;
  int bid = blockIdx.y * gridDim.x + blockIdx.x;
  bid = (bid & 7) * (nwg >> 3) + (bid >> 3);
  const int bn = (bid % (int)gridDim.x) * 256;
  const int bm = (bid / (int)gridDim.x) * 256;

  const int t8 = tid >> 3;
  const int kg = ((tid & 7) ^ (t8 & 7)) << 3;
  const unsigned short *aS0[2], *aS1[2], *bS0[2], *bS1[2];
#pragma unroll
  for (int g = 0; g < 2; ++g) {
    aS0[g] = A + (size_t)(bm + g * 128 + t8) * K + kg;
    aS1[g] = A + (size_t)(bm + g * 128 + 64 + t8) * K + kg;
    const int br = (g * 2 + (t8 >> 5)) * 64 + (t8 & 31);
    bS0[g] = Bt + (size_t)(bn + br) * K + kg;
    bS1[g] = Bt + (size_t)(bn + br + 32) * K + kg;
  }

#define STAGE(dst, half, src, koff)                                             \
  do {                                                                          \
    GLOAD16((src)[0] + (koff), &(dst)[((half) * 128 + 0) * 64 + wave * 512]);   \
    GLOAD16((src)[1] + (koff), &(dst)[((half) * 128 + 64) * 64 + wave * 512]);  \
  } while (0)

#define LDA_(DST, MH)                                                             \
  _Pragma("unroll") for (int ks = 0; ks < 2; ++ks)                                \
  _Pragma("unroll") for (int i = 0; i < 4; ++i)                                   \
      DST[ks][i] = *(const bf16x8*)&cA[((MH) * 128 + wm * 64 + i * 16 + n16) * 64 \
                                       + ((quad * 8 + ks * 32) ^ ((n16 & 7) << 3))];

#define LDB_(DST, NH)                                                             \
  _Pragma("unroll") for (int ks = 0; ks < 2; ++ks)                                \
  _Pragma("unroll") for (int jj = 0; jj < 2; ++jj)                                \
      DST[ks][jj] = *(const bf16x8*)&cB[((NH) * 128 + wn * 32 + jj * 16 + n16) * 64 \
                                        + ((quad * 8 + ks * 32) ^ ((n16 & 7) << 3))];

#define MFQ(MH, NH, AF, BF)                                                       \
  do {                                                                            \
    __builtin_amdgcn_s_setprio(1);                                                \
    _Pragma("unroll") for (int ks = 0; ks < 2; ++ks)                              \
    _Pragma("unroll") for (int i = 0; i < 4; ++i)                                 \
    _Pragma("unroll") for (int jj = 0; jj < 2; ++jj)                              \
        acc[(MH) * 4 + i][(NH) * 2 + jj] = __builtin_amdgcn_mfma_f32_16x16x32_bf16( \
            AF[ks][i], BF[ks][jj], acc[(MH) * 4 + i][(NH) * 2 + jj], 0, 0, 0);    \
    __builtin_amdgcn_s_setprio(0);                                                \
  } while (0)

  f32x4 acc[8][4];
#pragma unroll
  for (int mi = 0; mi < 8; ++mi)
#pragma unroll
    for (int ni = 0; ni < 4; ++ni) acc[mi][ni] = (f32x4){0.f, 0.f, 0.f, 0.f};

  bf16x8 aF[2][4], aG[2][4], b0F[2][2], b1F[2][2];

  // prologue: tile 0 (8 loads outstanding)
  STAGE(As[0], 0, aS0, 0);
  STAGE(Bs[0], 0, bS0, 0);
  STAGE(Bs[0], 1, bS1, 0);
  STAGE(As[0], 1, aS1, 0);

  for (int kt = 0; kt < KT - 1; ++kt) {
    const unsigned short* cA = As[kt & 1];
    const unsigned short* cB = Bs[kt & 1];
    unsigned short* nA = As[(kt & 1) ^ 1];
    unsigned short* nB = Bs[(kt & 1) ^ 1];
    const int ko = (kt + 1) * 64;

    // stage tile kt+1 (8 gloads); then tile kt's 8 are the oldest outstanding
    STAGE(nA, 0, aS0, ko);
    STAGE(nB, 0, bS0, ko);
    STAGE(nB, 1, bS1, ko);
    STAGE(nA, 1, aS1, ko);
    asm volatile("s_waitcnt vmcnt(8)" ::: "memory");   // tile kt landed (own); BAR => all waves'
    BAR();

    // open region: 24 ds_reads + 64 MFMAs, no internal barriers
    LDA_(aF, 0);
    LDB_(b0F, 0);
    LDB_(b1F, 1);
    MFQ(0, 0, aF, b0F);
    LDA_(aG, 1);            // half-1 A-loads hide under quadrant(0,0)'s MFMAs
    MFQ(0, 1, aF, b1F);
    MFQ(1, 1, aG, b1F);
    MFQ(1, 0, aG, b0F);

    BAR();   // WAR: close this tile's ds_reads before next iteration DMAs into this buffer
  }

  // peeled last tile: nothing more to issue; drain all
  {
    const unsigned short* cA = As[(KT - 1) & 1];
    const unsigned short* cB = Bs[(KT - 1) & 1];
    asm volatile("s_waitcnt vmcnt(0)" ::: "memory");
    BAR();
    LDA_(aF, 0);
    LDB_(b0F, 0);
    LDB_(b1F, 1);
    MFQ(0, 0, aF, b0F);
    LDA_(aG, 1);
    MFQ(0, 1, aF, b1F);
    MFQ(1, 1, aG, b1F);
    MFQ(1, 0, aG, b0F);
  }

  // ---- epilogue ----
#pragma unroll
  for (int mi = 0; mi < 8; ++mi) {
#pragma unroll
    for (int rr = 0; rr < 4; ++rr) {
      const int row = bm + wm * 128 + mi * 16 + quad * 4 + rr;
      if (EPI == 0) {
#pragma unroll
        for (int ni = 0; ni < 4; ++ni) {
          const int col = bn + wn * 64 + ni * 16 + n16;
          C[(size_t)row * N + col] = acc[mi][ni][rr];
        }
      } else {
        const int b = row >> 11, t = row & (T_ - 1);
#pragma unroll
        for (int ni = 0; ni < 4; ++ni) {
          const int col = bn + wn * 64 + ni * 16 + n16;
          const int hd = col & 127;
          float v = acc[mi][ni][rr];
          const float other = __shfl_xor(v, 1);   // RoPE pair (col^1), all lanes execute
          if (col < 2560 && hd < RD_) {
            const float c = cosb[t * 32 + (hd >> 1)];
            const float s = sinb[t * 32 + (hd >> 1)];
            v = (col & 1) ? (other * s + v * c) : (v * c - other * s);
          }
          if (col < 2048) {
            Qbf[(size_t)row * (H_ * HD_) + col] = f2bu(v * SCALE_);
          } else if (col < 2560) {
            const int kv = (col - 2048) >> 7;
            const size_t idx = (((size_t)(b * KV_ + kv) * T_) + t) * HD_ + hd;
            kout[idx] = v;
            Kbf[idx] = f2bu(v);
          } else {
            const int kv = (col - 2560) >> 7;
            vout[(((size_t)(b * KV_ + kv) * T_) + t) * HD_ + hd] = v;
          }
        }
      }
    }
  }
#undef STAGE
#undef LDA_
#undef LDB_
#undef MFQ
}

// ---------------- V transpose: vout f32 [G,T,HD] -> VbfT bf16 [G,HD,T], pi-permuted ----------------
// Keys within each 32-key chunk stored in the MFMA A-frag contraction order of the attention
// P fragment: 4 consecutive source keys kc..kc+3 land at slot base ((kc&15)<<1)|((kc&16)>>2).
__global__ __launch_bounds__(256) void v_transpose(const float* __restrict__ vin,
                                                   unsigned short* __restrict__ vt) {
  __shared__ unsigned int tile[32][17];
  const int tid = threadIdx.x;
  const int k0 = blockIdx.x * 32;
  const int d0 = blockIdx.y * 32;
  const int g  = blockIdx.z;
  const float* src = vin + ((size_t)g * T_ + k0) * HD_ + d0;

  {
    const int kr = tid >> 3;
    const int d2 = (tid & 7) * 2;
#pragma unroll
    for (int c = 0; c < 2; ++c) {
      const float2 f = *(const float2*)(src + (size_t)kr * HD_ + (d2 + c) * 2);
      tile[kr][d2 + c] = (unsigned)f2bu(f.x) | ((unsigned)f2bu(f.y) << 16);
    }
  }
  __syncthreads();
  {
    const int dr = tid >> 3;
    const int kc = (tid & 7) * 4;
    const int dstb = ((kc & 15) << 1) | ((kc & 16) >> 2);
    const int hi = dr >> 1;
    const int sh = (dr & 1) * 16;
    ushort4 o;
    o.x = (unsigned short)(tile[kc + 0][hi] >> sh);
    o.y = (unsigned short)(tile[kc + 1][hi] >> sh);
    o.z = (unsigned short)(tile[kc + 2][hi] >> sh);
    o.w = (unsigned short)(tile[kc + 3][hi] >> sh);
    *(ushort4*)(vt + ((size_t)g * HD_ + d0 + dr) * T_ + k0 + dstb) = o;
  }
}

// ---------------- flash attention v5: paired q-tiles, swapped QK^T, bf16 Q, shfl broadcasts ----------------
// Block = (pair pid, b, kvh): tile A = qt pid, tile B = qt 127-pid -> equal work per block.
// Q is pre-rope'd, pre-scaled bf16 (from gemm256<1>) -> frag load is a single b128 per slice.
// Alpha / l broadcasts via __shfl (wave-uniform branches) instead of LDS round-trips.
__global__ __launch_bounds__(256, 2) void attn_flash(const unsigned short* __restrict__ Q,
                                                     const unsigned short* __restrict__ Kbf,
                                                     const unsigned short* __restrict__ VbfT,
                                                     unsigned short* __restrict__ O) {
  __shared__ __align__(16) unsigned short Ks[32 * 128];  // [key][d], swizzled
  __shared__ __align__(16) unsigned short Vs[128 * 32];  // [d][key-slot], swizzled

  const int tid = threadIdx.x;
  const int wave = tid >> 6;        // = head within kv group
  const int lane = tid & 63;
  const int n16 = lane & 15;
  const int quad = lane >> 4;
  const int pid = blockIdx.x;       // 0..63
  const int q0A = pid * 16;
  const int q0B = (127 - pid) * 16;
  const int nchA = (q0A + 47) >> 5;
  const int nchB = (q0B + 47) >> 5;
  const int bkv = blockIdx.y;
  const int b = bkv >> 2;
  const int kvh = bkv & 3;
  const int h = kvh * 4 + wave;

  const unsigned short* ksrc = Kbf + ((size_t)(b * KV_ + kvh)) * T_ * HD_;
  const unsigned short* vtsrc = VbfT + ((size_t)(b * KV_ + kvh)) * HD_ * T_;

  const int krow = tid >> 4;            // 0..15 (+16 for second op)
  const int kcol = (tid & 15) * 8;
  const int kdst0 = (krow * 128 + kcol) ^ ((krow & 7) << 3);
  const int kdst1 = ((krow + 16) * 128 + kcol) ^ ((krow & 7) << 3);
  const int vrow = tid >> 2;            // 0..63 (+64 for second op)
  const int vcol = (tid & 3) * 8;
  const int vdst0 = (vrow * 32 + vcol) ^ ((vrow & 3) << 3);
  const int vdst1 = ((vrow + 64) * 32 + vcol) ^ ((vrow & 3) << 3);

  // Q A-frags (bf16, rope'd, pre-scaled); lane n16 owns q-row q0+n16
  bf16x8 qfA[4], qfB[4];
  {
    const unsigned short* qa = Q + ((size_t)(b * T_ + q0A + n16)) * (H_ * HD_) + h * HD_ + quad * 8;
    const unsigned short* qb = Q + ((size_t)(b * T_ + q0B + n16)) * (H_ * HD_) + h * HD_ + quad * 8;
#pragma unroll
    for (int s = 0; s < 4; ++s) {
      qfA[s] = *(const bf16x8*)(qa + s * 32);
      qfB[s] = *(const bf16x8*)(qb + s * 32);
    }
  }

  float mA = -1e30f, lA = 0.f;
  float mB = -1e30f, lB = 0.f;
  f32x4 oA[8], oB[8];
#pragma unroll
  for (int t = 0; t < 8; ++t) { oA[t] = (f32x4){0.f,0.f,0.f,0.f}; oB[t] = (f32x4){0.f,0.f,0.f,0.f}; }

  // stage chunk 0
  {
    const u16x8 ka = *(const u16x8*)(ksrc + (size_t)krow * HD_ + kcol);
    const u16x8 kb = *(const u16x8*)(ksrc + (size_t)(krow + 16) * HD_ + kcol);
    const u16x8 va = *(const u16x8*)(vtsrc + (size_t)vrow * T_ + vcol);
    const u16x8 vb = *(const u16x8*)(vtsrc + (size_t)(vrow + 64) * T_ + vcol);
    *(u16x8*)&Ks[kdst0] = ka;
    *(u16x8*)&Ks[kdst1] = kb;
    *(u16x8*)&Vs[vdst0] = va;
    *(u16x8*)&Vs[vdst1] = vb;
  }
  __syncthreads();

  for (int c = 0; c < nchB; ++c) {
    const int kc = c * 32;
    const bool actA = (c < nchA);

    // prefetch next chunk to regs; LDS writes happen after the post-compute barrier
    u16x8 ka, kb, va, vb;
    if (c + 1 < nchB) {
      ka = *(const u16x8*)(ksrc + (size_t)(kc + 32 + krow) * HD_ + kcol);
      kb = *(const u16x8*)(ksrc + (size_t)(kc + 48 + krow) * HD_ + kcol);
      va = *(const u16x8*)(vtsrc + (size_t)vrow * T_ + (kc + 32) + vcol);
      vb = *(const u16x8*)(vtsrc + (size_t)(vrow + 64) * T_ + (kc + 32) + vcol);
    }
    COMPILER_BARRIER();

    // ---- swapped QK^T, K-frags shared by both tiles ----
    f32x4 sB0 = (f32x4){0.f,0.f,0.f,0.f}, sB1 = sB0, sA0 = sB0, sA1 = sB0;
#pragma unroll
    for (int s = 0; s < 4; ++s) {
      const bf16x8 kf0 = *(const bf16x8*)&Ks[(n16 * 128 + quad * 8 + s * 32) ^ ((n16 & 7) << 3)];
      const bf16x8 kf1 = *(const bf16x8*)&Ks[((16 + n16) * 128 + quad * 8 + s * 32) ^ ((n16 & 7) << 3)];
      sB0 = __builtin_amdgcn_mfma_f32_16x16x32_bf16(kf0, qfB[s], sB0, 0, 0, 0);
      sB1 = __builtin_amdgcn_mfma_f32_16x16x32_bf16(kf1, qfB[s], sB1, 0, 0, 0);
      if (actA) {
        sA0 = __builtin_amdgcn_mfma_f32_16x16x32_bf16(kf0, qfA[s], sA0, 0, 0, 0);
        sA1 = __builtin_amdgcn_mfma_f32_16x16x32_bf16(kf1, qfA[s], sA1, 0, 0, 0);
      }
    }

    // ---- softmax B (lane-local row q0B+n16; s[] already in A-frag slot order) ----
    union { bf16x8 v; unsigned short u[8]; } pkB, pkA;
    bool growB;
    float alphaB = 1.f, alphaA = 1.f;
    {
      float s[8];
#pragma unroll
      for (int r = 0; r < 4; ++r) { s[r] = sB0[r]; s[r + 4] = sB1[r]; }
      if (c == nchB - 1) {
        const int qrow = q0B + n16;
#pragma unroll
        for (int r = 0; r < 4; ++r) {
          if (kc + quad * 4 + r > qrow)      s[r]     = -1e30f;
          if (kc + 16 + quad * 4 + r > qrow) s[r + 4] = -1e30f;
        }
      }
      float mm = fmaxf(fmaxf(fmaxf(s[0], s[1]), fmaxf(s[2], s[3])),
                       fmaxf(fmaxf(s[4], s[5]), fmaxf(s[6], s[7])));
      mm = fmaxf(mm, __shfl_xor(mm, 16));
      mm = fmaxf(mm, __shfl_xor(mm, 32));
      growB = __any(mm > mB);
      if (growB) {
        const float mnew = fmaxf(mB, mm);
        alphaB = __expf(mB - mnew);
        mB = mnew;
      }
      float lsum = 0.f;
#pragma unroll
      for (int j = 0; j < 8; ++j) {
        const float p = __expf(s[j] - mB);
        lsum += p;
        pkB.u[j] = f2bu(p);
      }
      lsum += __shfl_xor(lsum, 16);
      lsum += __shfl_xor(lsum, 32);
      lB = growB ? (alphaB * lB + lsum) : (lB + lsum);
    }

    // ---- softmax A ----
    bool growA = false;
    if (actA) {
      float s[8];
#pragma unroll
      for (int r = 0; r < 4; ++r) { s[r] = sA0[r]; s[r + 4] = sA1[r]; }
      if (c == nchA - 1) {
        const int qrow = q0A + n16;
#pragma unroll
        for (int r = 0; r < 4; ++r) {
          if (kc + quad * 4 + r > qrow)      s[r]     = -1e30f;
          if (kc + 16 + quad * 4 + r > qrow) s[r + 4] = -1e30f;
        }
      }
      float mm = fmaxf(fmaxf(fmaxf(s[0], s[1]), fmaxf(s[2], s[3])),
                       fmaxf(fmaxf(s[4], s[5]), fmaxf(s[6], s[7])));
      mm = fmaxf(mm, __shfl_xor(mm, 16));
      mm = fmaxf(mm, __shfl_xor(mm, 32));
      growA = __any(mm > mA);
      if (growA) {
        const float mnew = fmaxf(mA, mm);
        alphaA = __expf(mA - mnew);
        mA = mnew;
      }
      float lsum = 0.f;
#pragma unroll
      for (int j = 0; j < 8; ++j) {
        const float p = __expf(s[j] - mA);
        lsum += p;
        pkA.u[j] = f2bu(p);
      }
      lsum += __shfl_xor(lsum, 16);
      lsum += __shfl_xor(lsum, 32);
      lA = growA ? (alphaA * lA + lsum) : (lA + lsum);
    }

    // ---- O rescale only when max grew; alpha broadcast row->C-layout via shfl ----
    if (growB) {
      f32x4 av;
#pragma unroll
      for (int r = 0; r < 4; ++r) av[r] = __shfl(alphaB, quad * 4 + r);
#pragma unroll
      for (int t = 0; t < 8; ++t) {
        oB[t][0] *= av[0]; oB[t][1] *= av[1]; oB[t][2] *= av[2]; oB[t][3] *= av[3];
      }
    }
    if (growA) {
      f32x4 av;
#pragma unroll
      for (int r = 0; r < 4; ++r) av[r] = __shfl(alphaA, quad * 4 + r);
#pragma unroll
      for (int t = 0; t < 8; ++t) {
        oA[t][0] *= av[0]; oA[t][1] *= av[1]; oA[t][2] *= av[2]; oA[t][3] *= av[3];
      }
    }

    // ---- PV, V-frags shared by both tiles (pi-permuted layout matches pk order) ----
#pragma unroll
    for (int t = 0; t < 8; ++t) {
      const bf16x8 vf = *(const bf16x8*)&Vs[((t * 16 + n16) * 32 + quad * 8) ^ ((n16 & 3) << 3)];
      oB[t] = __builtin_amdgcn_mfma_f32_16x16x32_bf16(pkB.v, vf, oB[t], 0, 0, 0);
      if (actA) oA[t] = __builtin_amdgcn_mfma_f32_16x16x32_bf16(pkA.v, vf, oA[t], 0, 0, 0);
    }

    __syncthreads();      // all waves done reading this chunk's K/V tiles
    if (c + 1 < nchB) {
      *(u16x8*)&Ks[kdst0] = ka;
      *(u16x8*)&Ks[kdst1] = kb;
      *(u16x8*)&Vs[vdst0] = va;
      *(u16x8*)&Vs[vdst1] = vb;
    }
    __syncthreads();      // next chunk's tiles visible to all waves
  }

  // ---- epilogue: normalize (l via shfl), store bf16 (both tiles) ----
  {
    unsigned short* obB = O + ((size_t)(b * T_ + q0B)) * (H_ * HD_) + h * HD_;
    unsigned short* obA = O + ((size_t)(b * T_ + q0A)) * (H_ * HD_) + h * HD_;
#pragma unroll
    for (int r = 0; r < 4; ++r) {
      const float liB = 1.0f / __shfl(lB, quad * 4 + r);
      const float liA = 1.0f / __shfl(lA, quad * 4 + r);
#pragma unroll
      for (int t = 0; t < 8; ++t) {
        obB[(size_t)(quad * 4 + r) * (H_ * HD_) + t * 16 + n16] = f2bu(oB[t][r] * liB);
        obA[(size_t)(quad * 4 + r) * (H_ * HD_) + t * 16 + n16] = f2bu(oA[t][r] * liA);
      }
    }
  }
}

extern "C" void kernel_launch(void* const* d_in, const int* in_sizes, int n_in,
                              void* d_out, int out_size, void* d_ws, size_t ws_size,
                              hipStream_t stream) {
  const float* x  = (const float*)d_in[0];
  const float* fc = (const float*)d_in[1];
  const float* fs = (const float*)d_in[2];
  const float* Wq = (const float*)d_in[3];
  const float* Wk = (const float*)d_in[4];
  const float* Wv = (const float*)d_in[5];
  const float* Wo = (const float*)d_in[6];

  // Outputs (f32), concatenated: y | present_k | present_v
  float* yout = (float*)d_out;                          // [B,T,D]
  float* kout = yout + (size_t)B_ * T_ * D_;            // [B,KV,T,HD]
  float* vout = kout + (size_t)B_ * KV_ * T_ * HD_;     // [B,KV,T,HD]
  unsigned short* Qbf = (unsigned short*)yout;          // bf16 Q staging in yout region

  // workspace (bf16, 44 MB): xb/Abf (aliased) | Wqt | Wkvt | Wot | Kbf | VbfT
  unsigned short* xb   = (unsigned short*)d_ws;                    // [BT, D]
  unsigned short* Abf  = xb;                                       // alias: xb dead after gemm256<1>
  unsigned short* Wqt  = xb   + (size_t)BT_ * D_;                  // [2048, 2048]
  unsigned short* Wkvt = Wqt  + (size_t)D_ * D_;                   // [1024, 2048] (contiguous after Wqt)
  unsigned short* Wot  = Wkvt + (size_t)1024 * D_;                 // [2048, 2048]
  unsigned short* Kbf  = Wot  + (size_t)D_ * D_;                   // [B,KV,T,HD]
  unsigned short* VbfT = Kbf  + (size_t)B_ * KV_ * T_ * HD_;       // [B*KV, HD, T] (pi-permuted)

  dim3 blk(256);

  // input conversions
  cvt_bf16<<<dim3((BT_ * D_) / 1024), blk, 0, stream>>>(x, xb);
  t32_all<<<dim3(D_ / 32, D_ / 32, 4), blk, 0, stream>>>(Wq, Wk, Wv, Wo, Wqt, Wkvt, Wot);

  // fused QKV projection + RoPE (256^2 counted-vmcnt; Bt = Wqt||Wkvt contiguous)
  gemm256<1><<<dim3(NPROJ_ / 256, BT_ / 256), dim3(512), 0, stream>>>(
      xb, Wqt, nullptr, Qbf, kout, vout, Kbf, fc, fs, NPROJ_);

  // V^T bf16 mirror (pi-permuted)
  v_transpose<<<dim3(T_ / 32, HD_ / 32, B_ * KV_), blk, 0, stream>>>(vout, VbfT);

  // flash attention v5: 512 equal-work paired blocks, 4 waves each
  attn_flash<<<dim3(64, B_ * KV_), blk, 0, stream>>>(Qbf, Kbf, VbfT, Abf);

  // output projection (256^2 counted-vmcnt); overwrites Qbf staging with y
  gemm256<0><<<dim3(D_ / 256, BT_ / 256), dim3(512), 0, stream>>>(
      Abf, Wot, yout, nullptr, nullptr, nullptr, nullptr, nullptr, nullptr, D_);
}

// Round 11
// 364.556 us; speedup vs baseline: 1.0722x; 1.0593x over previous
//
#include <hip/hip_runtime.h>
#include <hip/hip_bf16.h>

// Problem constants (B,T,D,H,KV,HD,RD from reference)
static constexpr int B_  = 2;
static constexpr int T_  = 2048;
static constexpr int D_  = 2048;
static constexpr int H_  = 16;
static constexpr int KV_ = 4;
static constexpr int HD_ = 128;
static constexpr int RD_ = 64;
static constexpr int BT_ = B_ * T_;           // 4096
static constexpr int NPROJ_ = 3072;           // Q(2048) | K(512) | V(512) fused
static constexpr float SCALE_ = 0.08838834764831845f; // 1/sqrt(128)

typedef __attribute__((ext_vector_type(8))) short bf16x8;
typedef __attribute__((ext_vector_type(8))) unsigned short u16x8;
typedef __attribute__((ext_vector_type(4))) float f32x4;

#define COMPILER_BARRIER() __asm__ __volatile__("" ::: "memory")
#define BAR() do { COMPILER_BARRIER(); __builtin_amdgcn_s_barrier(); COMPILER_BARRIER(); } while (0)

// async global->LDS DMA, 16B per lane; LDS dest = wave-uniform base + lane*16
typedef const __attribute__((address_space(1))) unsigned int* as1_u32p;
typedef __attribute__((address_space(3))) unsigned int* as3_u32p;
#define GLOAD16(g, l) __builtin_amdgcn_global_load_lds((as1_u32p)(const void*)(g), (as3_u32p)(void*)(l), 16, 0, 0)

// f32 -> bf16 (RNE) raw bits
__device__ __forceinline__ unsigned short f2bu(float f) {
  unsigned x = __float_as_uint(f);
  unsigned r = (x + 0x7fffu + ((x >> 16) & 1u)) >> 16;
  return (unsigned short)r;
}

// ---------------- f32 -> bf16 elementwise (n divisible by 1024) ----------------
__global__ __launch_bounds__(256) void cvt_bf16(const float* __restrict__ in,
                                                unsigned short* __restrict__ out) {
  const size_t i = ((size_t)blockIdx.x * 256 + threadIdx.x) * 4;
  const float4 f = *(const float4*)(in + i);
  ushort4 o;
  o.x = f2bu(f.x); o.y = f2bu(f.y); o.z = f2bu(f.z); o.w = f2bu(f.w);
  *(ushort4*)(out + i) = o;
}

// ---------------- all 4 weight transposes in ONE launch: f32 [R,C] -> bf16 [C,R] ----------------
__global__ __launch_bounds__(256) void t32_all(const float* __restrict__ Wq,
                                               const float* __restrict__ Wk,
                                               const float* __restrict__ Wv,
                                               const float* __restrict__ Wo,
                                               unsigned short* __restrict__ Wqt,
                                               unsigned short* __restrict__ Wkvt,
                                               unsigned short* __restrict__ Wot) {
  const float* in; unsigned short* out; int C;
  switch (blockIdx.z) {
    case 0:  in = Wq; out = Wqt;                       C = 2048; break;
    case 1:  in = Wk; out = Wkvt;                      C = 512;  break;
    case 2:  in = Wv; out = Wkvt + (size_t)512 * D_;   C = 512;  break;
    default: in = Wo; out = Wot;                       C = 2048; break;
  }
  if ((int)blockIdx.y * 32 >= C) return;   // Wk/Wv only span 16 y-blocks

  __shared__ unsigned short tile[32][36];
  const int r0 = blockIdx.x * 32;
  const int c0 = blockIdx.y * 32;
  const int tid = threadIdx.x;
  {
    const int r = tid >> 3;
    const int c = (tid & 7) * 4;
    const float4 f = *(const float4*)(in + (size_t)(r0 + r) * C + c0 + c);
    ushort4 w;
    w.x = f2bu(f.x); w.y = f2bu(f.y); w.z = f2bu(f.z); w.w = f2bu(f.w);
    *(ushort4*)&tile[r][c] = w;
  }
  __syncthreads();
  {
    const int c = tid >> 3;
    const int r = (tid & 7) * 4;
    ushort4 o;
    o.x = tile[r + 0][c];
    o.y = tile[r + 1][c];
    o.z = tile[r + 2][c];
    o.w = tile[r + 3][c];
    *(ushort4*)(out + (size_t)(c0 + c) * D_ + r0 + r) = o;
  }
}

// ---------------- 128x128 bf16 GEMM: T2 swizzle + counted vmcnt, 2 blocks/CU ----------------
// R11: retiled from 256^2 (1 block/CU, grid 128-192 blocks = half GPU idle) to 128^2:
// 4 waves (2Mx2N, 64x64/wave), BK=64, LDS 64 KiB dbuf -> 2 blocks/CU co-resident
// (m97-style implicit inter-block overlap). Grids: proj 768 blocks, out-proj 512 blocks.
// Per K-tile: stage next tile's 8 gloads (linear LDS dest + pre-swizzled global source)
// -> vmcnt(8) (current tile's own 8 retired; BAR => all waves') -> BAR -> 16 ds_reads +
// 32 MFMAs (open region) -> BAR (WAR: reads closed before next iter DMAs this buffer).
// Peeled last tile drains vmcnt(0). EPI=0: f32 C. EPI=1: fused QKV+RoPE epilogue.
template <int EPI>
__global__ __launch_bounds__(256, 2) void gemm128(const unsigned short* __restrict__ A,
                                                  const unsigned short* __restrict__ Bt,
                                                  float* __restrict__ C,
                                                  unsigned short* __restrict__ Qbf,
                                                  float* __restrict__ kout,
                                                  float* __restrict__ vout,
                                                  unsigned short* __restrict__ Kbf,
                                                  const float* __restrict__ cosb,
                                                  const float* __restrict__ sinb,
                                                  int N) {
  __shared__ __align__(16) unsigned short As[2][128 * 64];
  __shared__ __align__(16) unsigned short Bs[2][128 * 64];
  constexpr int K = D_;          // 2048
  constexpr int KT = K / 64;     // 32

  const int tid = threadIdx.x;
  const int lane = tid & 63;
  const int wave = tid >> 6;     // 0..3
  const int n16 = lane & 15;
  const int quad = lane >> 4;
  const int wm = wave >> 1;      // 0..1
  const int wn = wave & 1;       // 0..1

  // XCD-aware bijective swizzle (both grids have nwg % 8 == 0)
  const int nwg = gridDim.x * gridDim.y;
  int bid = blockIdx.y * gridDim.x + blockIdx.x;
  bid = (bid & 7) * (nwg >> 3) + (bid >> 3);
  const int bn = (bid % (int)gridDim.x) * 128;
  const int bm = (bid / (int)gridDim.x) * 128;

  // staging: 4 ops per matrix tile; op g covers rows g*32 + (tid>>3), slot tid&7;
  // source k-group = slot ^ (row&7) (pre-swizzle); linear LDS dest in lane order.
  const int t5 = tid >> 3;              // 0..31
  const int kg = ((tid & 7) ^ (t5 & 7)) << 3;
  const unsigned short *aS[4], *bS[4];
#pragma unroll
  for (int g = 0; g < 4; ++g) {
    aS[g] = A  + (size_t)(bm + g * 32 + t5) * K + kg;
    bS[g] = Bt + (size_t)(bn + g * 32 + t5) * K + kg;
  }

#define STAGE_A(dst, koff)                                     \
  _Pragma("unroll") for (int g = 0; g < 4; ++g)                \
      GLOAD16(aS[g] + (koff), &(dst)[g * 2048 + wave * 512]);

#define STAGE_B(dst, koff)                                     \
  _Pragma("unroll") for (int g = 0; g < 4; ++g)                \
      GLOAD16(bS[g] + (koff), &(dst)[g * 2048 + wave * 512]);

#define LDFRAGS(cA, cB)                                                             \
  do {                                                                              \
    _Pragma("unroll") for (int ks = 0; ks < 2; ++ks)                                \
    _Pragma("unroll") for (int i = 0; i < 4; ++i)                                   \
        aF[ks][i] = *(const bf16x8*)&(cA)[(wm * 64 + i * 16 + n16) * 64             \
                                          + ((quad * 8 + ks * 32) ^ ((n16 & 7) << 3))]; \
    _Pragma("unroll") for (int ks = 0; ks < 2; ++ks)                                \
    _Pragma("unroll") for (int jj = 0; jj < 4; ++jj)                                \
        bF[ks][jj] = *(const bf16x8*)&(cB)[(wn * 64 + jj * 16 + n16) * 64           \
                                           + ((quad * 8 + ks * 32) ^ ((n16 & 7) << 3))]; \
  } while (0)

#define MFALL()                                                                     \
  do {                                                                              \
    __builtin_amdgcn_s_setprio(1);                                                  \
    _Pragma("unroll") for (int ks = 0; ks < 2; ++ks)                                \
    _Pragma("unroll") for (int i = 0; i < 4; ++i)                                   \
    _Pragma("unroll") for (int jj = 0; jj < 4; ++jj)                                \
        acc[i][jj] = __builtin_amdgcn_mfma_f32_16x16x32_bf16(                       \
            aF[ks][i], bF[ks][jj], acc[i][jj], 0, 0, 0);                            \
    __builtin_amdgcn_s_setprio(0);                                                  \
  } while (0)

  f32x4 acc[4][4];
#pragma unroll
  for (int mi = 0; mi < 4; ++mi)
#pragma unroll
    for (int ni = 0; ni < 4; ++ni) acc[mi][ni] = (f32x4){0.f, 0.f, 0.f, 0.f};

  bf16x8 aF[2][4], bF[2][4];

  // prologue: tile 0 (8 loads outstanding)
  STAGE_A(As[0], 0);
  STAGE_B(Bs[0], 0);

  for (int kt = 0; kt < KT - 1; ++kt) {
    const unsigned short* cA = As[kt & 1];
    const unsigned short* cB = Bs[kt & 1];
    unsigned short* nA = As[(kt & 1) ^ 1];
    unsigned short* nB = Bs[(kt & 1) ^ 1];
    const int ko = (kt + 1) * 64;

    // stage tile kt+1 (8 gloads); tile kt's 8 become the oldest outstanding
    STAGE_A(nA, ko);
    STAGE_B(nB, ko);
    asm volatile("s_waitcnt vmcnt(8)" ::: "memory");   // tile kt landed (own); BAR => all waves'
    BAR();

    LDFRAGS(cA, cB);      // 16 ds_read_b128, conflict-swizzled
    MFALL();              // 32 MFMAs

    BAR();   // WAR: close this tile's ds_reads before next iteration DMAs into this buffer
  }

  // peeled last tile: nothing more to issue; drain all
  {
    const unsigned short* cA = As[(KT - 1) & 1];
    const unsigned short* cB = Bs[(KT - 1) & 1];
    asm volatile("s_waitcnt vmcnt(0)" ::: "memory");
    BAR();
    LDFRAGS(cA, cB);
    MFALL();
  }

  // ---- epilogue ----
#pragma unroll
  for (int mi = 0; mi < 4; ++mi) {
#pragma unroll
    for (int rr = 0; rr < 4; ++rr) {
      const int row = bm + wm * 64 + mi * 16 + quad * 4 + rr;
      if (EPI == 0) {
#pragma unroll
        for (int ni = 0; ni < 4; ++ni) {
          const int col = bn + wn * 64 + ni * 16 + n16;
          C[(size_t)row * N + col] = acc[mi][ni][rr];
        }
      } else {
        const int b = row >> 11, t = row & (T_ - 1);
#pragma unroll
        for (int ni = 0; ni < 4; ++ni) {
          const int col = bn + wn * 64 + ni * 16 + n16;
          const int hd = col & 127;
          float v = acc[mi][ni][rr];
          const float other = __shfl_xor(v, 1);   // RoPE pair (col^1), all lanes execute
          if (col < 2560 && hd < RD_) {
            const float c = cosb[t * 32 + (hd >> 1)];
            const float s = sinb[t * 32 + (hd >> 1)];
            v = (col & 1) ? (other * s + v * c) : (v * c - other * s);
          }
          if (col < 2048) {
            Qbf[(size_t)row * (H_ * HD_) + col] = f2bu(v * SCALE_);
          } else if (col < 2560) {
            const int kv = (col - 2048) >> 7;
            const size_t idx = (((size_t)(b * KV_ + kv) * T_) + t) * HD_ + hd;
            kout[idx] = v;
            Kbf[idx] = f2bu(v);
          } else {
            const int kv = (col - 2560) >> 7;
            vout[(((size_t)(b * KV_ + kv) * T_) + t) * HD_ + hd] = v;
          }
        }
      }
    }
  }
#undef STAGE_A
#undef STAGE_B
#undef LDFRAGS
#undef MFALL
}

// ---------------- V transpose: vout f32 [G,T,HD] -> VbfT bf16 [G,HD,T], pi-permuted ----------------
// Keys within each 32-key chunk stored in the MFMA A-frag contraction order of the attention
// P fragment: 4 consecutive source keys kc..kc+3 land at slot base ((kc&15)<<1)|((kc&16)>>2).
__global__ __launch_bounds__(256) void v_transpose(const float* __restrict__ vin,
                                                   unsigned short* __restrict__ vt) {
  __shared__ unsigned int tile[32][17];
  const int tid = threadIdx.x;
  const int k0 = blockIdx.x * 32;
  const int d0 = blockIdx.y * 32;
  const int g  = blockIdx.z;
  const float* src = vin + ((size_t)g * T_ + k0) * HD_ + d0;

  {
    const int kr = tid >> 3;
    const int d2 = (tid & 7) * 2;
#pragma unroll
    for (int c = 0; c < 2; ++c) {
      const float2 f = *(const float2*)(src + (size_t)kr * HD_ + (d2 + c) * 2);
      tile[kr][d2 + c] = (unsigned)f2bu(f.x) | ((unsigned)f2bu(f.y) << 16);
    }
  }
  __syncthreads();
  {
    const int dr = tid >> 3;
    const int kc = (tid & 7) * 4;
    const int dstb = ((kc & 15) << 1) | ((kc & 16) >> 2);
    const int hi = dr >> 1;
    const int sh = (dr & 1) * 16;
    ushort4 o;
    o.x = (unsigned short)(tile[kc + 0][hi] >> sh);
    o.y = (unsigned short)(tile[kc + 1][hi] >> sh);
    o.z = (unsigned short)(tile[kc + 2][hi] >> sh);
    o.w = (unsigned short)(tile[kc + 3][hi] >> sh);
    *(ushort4*)(vt + ((size_t)g * HD_ + d0 + dr) * T_ + k0 + dstb) = o;
  }
}

// ---------------- flash attention v5: paired q-tiles, swapped QK^T, bf16 Q, shfl broadcasts ----------------
// Block = (pair pid, b, kvh): tile A = qt pid, tile B = qt 127-pid -> equal work per block.
// Q is pre-rope'd, pre-scaled bf16 (from gemm128<1>) -> frag load is a single b128 per slice.
// Alpha / l broadcasts via __shfl (wave-uniform branches) instead of LDS round-trips.
__global__ __launch_bounds__(256, 2) void attn_flash(const unsigned short* __restrict__ Q,
                                                     const unsigned short* __restrict__ Kbf,
                                                     const unsigned short* __restrict__ VbfT,
                                                     unsigned short* __restrict__ O) {
  __shared__ __align__(16) unsigned short Ks[32 * 128];  // [key][d], swizzled
  __shared__ __align__(16) unsigned short Vs[128 * 32];  // [d][key-slot], swizzled

  const int tid = threadIdx.x;
  const int wave = tid >> 6;        // = head within kv group
  const int lane = tid & 63;
  const int n16 = lane & 15;
  const int quad = lane >> 4;
  const int pid = blockIdx.x;       // 0..63
  const int q0A = pid * 16;
  const int q0B = (127 - pid) * 16;
  const int nchA = (q0A + 47) >> 5;
  const int nchB = (q0B + 47) >> 5;
  const int bkv = blockIdx.y;
  const int b = bkv >> 2;
  const int kvh = bkv & 3;
  const int h = kvh * 4 + wave;

  const unsigned short* ksrc = Kbf + ((size_t)(b * KV_ + kvh)) * T_ * HD_;
  const unsigned short* vtsrc = VbfT + ((size_t)(b * KV_ + kvh)) * HD_ * T_;

  const int krow = tid >> 4;            // 0..15 (+16 for second op)
  const int kcol = (tid & 15) * 8;
  const int kdst0 = (krow * 128 + kcol) ^ ((krow & 7) << 3);
  const int kdst1 = ((krow + 16) * 128 + kcol) ^ ((krow & 7) << 3);
  const int vrow = tid >> 2;            // 0..63 (+64 for second op)
  const int vcol = (tid & 3) * 8;
  const int vdst0 = (vrow * 32 + vcol) ^ ((vrow & 3) << 3);
  const int vdst1 = ((vrow + 64) * 32 + vcol) ^ ((vrow & 3) << 3);

  // Q A-frags (bf16, rope'd, pre-scaled); lane n16 owns q-row q0+n16
  bf16x8 qfA[4], qfB[4];
  {
    const unsigned short* qa = Q + ((size_t)(b * T_ + q0A + n16)) * (H_ * HD_) + h * HD_ + quad * 8;
    const unsigned short* qb = Q + ((size_t)(b * T_ + q0B + n16)) * (H_ * HD_) + h * HD_ + quad * 8;
#pragma unroll
    for (int s = 0; s < 4; ++s) {
      qfA[s] = *(const bf16x8*)(qa + s * 32);
      qfB[s] = *(const bf16x8*)(qb + s * 32);
    }
  }

  float mA = -1e30f, lA = 0.f;
  float mB = -1e30f, lB = 0.f;
  f32x4 oA[8], oB[8];
#pragma unroll
  for (int t = 0; t < 8; ++t) { oA[t] = (f32x4){0.f,0.f,0.f,0.f}; oB[t] = (f32x4){0.f,0.f,0.f,0.f}; }

  // stage chunk 0
  {
    const u16x8 ka = *(const u16x8*)(ksrc + (size_t)krow * HD_ + kcol);
    const u16x8 kb = *(const u16x8*)(ksrc + (size_t)(krow + 16) * HD_ + kcol);
    const u16x8 va = *(const u16x8*)(vtsrc + (size_t)vrow * T_ + vcol);
    const u16x8 vb = *(const u16x8*)(vtsrc + (size_t)(vrow + 64) * T_ + vcol);
    *(u16x8*)&Ks[kdst0] = ka;
    *(u16x8*)&Ks[kdst1] = kb;
    *(u16x8*)&Vs[vdst0] = va;
    *(u16x8*)&Vs[vdst1] = vb;
  }
  __syncthreads();

  for (int c = 0; c < nchB; ++c) {
    const int kc = c * 32;
    const bool actA = (c < nchA);

    // prefetch next chunk to regs; LDS writes happen after the post-compute barrier
    u16x8 ka, kb, va, vb;
    if (c + 1 < nchB) {
      ka = *(const u16x8*)(ksrc + (size_t)(kc + 32 + krow) * HD_ + kcol);
      kb = *(const u16x8*)(ksrc + (size_t)(kc + 48 + krow) * HD_ + kcol);
      va = *(const u16x8*)(vtsrc + (size_t)vrow * T_ + (kc + 32) + vcol);
      vb = *(const u16x8*)(vtsrc + (size_t)(vrow + 64) * T_ + (kc + 32) + vcol);
    }
    COMPILER_BARRIER();

    // ---- swapped QK^T, K-frags shared by both tiles ----
    f32x4 sB0 = (f32x4){0.f,0.f,0.f,0.f}, sB1 = sB0, sA0 = sB0, sA1 = sB0;
#pragma unroll
    for (int s = 0; s < 4; ++s) {
      const bf16x8 kf0 = *(const bf16x8*)&Ks[(n16 * 128 + quad * 8 + s * 32) ^ ((n16 & 7) << 3)];
      const bf16x8 kf1 = *(const bf16x8*)&Ks[((16 + n16) * 128 + quad * 8 + s * 32) ^ ((n16 & 7) << 3)];
      sB0 = __builtin_amdgcn_mfma_f32_16x16x32_bf16(kf0, qfB[s], sB0, 0, 0, 0);
      sB1 = __builtin_amdgcn_mfma_f32_16x16x32_bf16(kf1, qfB[s], sB1, 0, 0, 0);
      if (actA) {
        sA0 = __builtin_amdgcn_mfma_f32_16x16x32_bf16(kf0, qfA[s], sA0, 0, 0, 0);
        sA1 = __builtin_amdgcn_mfma_f32_16x16x32_bf16(kf1, qfA[s], sA1, 0, 0, 0);
      }
    }

    // ---- softmax B (lane-local row q0B+n16; s[] already in A-frag slot order) ----
    union { bf16x8 v; unsigned short u[8]; } pkB, pkA;
    bool growB;
    float alphaB = 1.f, alphaA = 1.f;
    {
      float s[8];
#pragma unroll
      for (int r = 0; r < 4; ++r) { s[r] = sB0[r]; s[r + 4] = sB1[r]; }
      if (c == nchB - 1) {
        const int qrow = q0B + n16;
#pragma unroll
        for (int r = 0; r < 4; ++r) {
          if (kc + quad * 4 + r > qrow)      s[r]     = -1e30f;
          if (kc + 16 + quad * 4 + r > qrow) s[r + 4] = -1e30f;
        }
      }
      float mm = fmaxf(fmaxf(fmaxf(s[0], s[1]), fmaxf(s[2], s[3])),
                       fmaxf(fmaxf(s[4], s[5]), fmaxf(s[6], s[7])));
      mm = fmaxf(mm, __shfl_xor(mm, 16));
      mm = fmaxf(mm, __shfl_xor(mm, 32));
      growB = __any(mm > mB);
      if (growB) {
        const float mnew = fmaxf(mB, mm);
        alphaB = __expf(mB - mnew);
        mB = mnew;
      }
      float lsum = 0.f;
#pragma unroll
      for (int j = 0; j < 8; ++j) {
        const float p = __expf(s[j] - mB);
        lsum += p;
        pkB.u[j] = f2bu(p);
      }
      lsum += __shfl_xor(lsum, 16);
      lsum += __shfl_xor(lsum, 32);
      lB = growB ? (alphaB * lB + lsum) : (lB + lsum);
    }

    // ---- softmax A ----
    bool growA = false;
    if (actA) {
      float s[8];
#pragma unroll
      for (int r = 0; r < 4; ++r) { s[r] = sA0[r]; s[r + 4] = sA1[r]; }
      if (c == nchA - 1) {
        const int qrow = q0A + n16;
#pragma unroll
        for (int r = 0; r < 4; ++r) {
          if (kc + quad * 4 + r > qrow)      s[r]     = -1e30f;
          if (kc + 16 + quad * 4 + r > qrow) s[r + 4] = -1e30f;
        }
      }
      float mm = fmaxf(fmaxf(fmaxf(s[0], s[1]), fmaxf(s[2], s[3])),
                       fmaxf(fmaxf(s[4], s[5]), fmaxf(s[6], s[7])));
      mm = fmaxf(mm, __shfl_xor(mm, 16));
      mm = fmaxf(mm, __shfl_xor(mm, 32));
      growA = __any(mm > mA);
      if (growA) {
        const float mnew = fmaxf(mA, mm);
        alphaA = __expf(mA - mnew);
        mA = mnew;
      }
      float lsum = 0.f;
#pragma unroll
      for (int j = 0; j < 8; ++j) {
        const float p = __expf(s[j] - mA);
        lsum += p;
        pkA.u[j] = f2bu(p);
      }
      lsum += __shfl_xor(lsum, 16);
      lsum += __shfl_xor(lsum, 32);
      lA = growA ? (alphaA * lA + lsum) : (lA + lsum);
    }

    // ---- O rescale only when max grew; alpha broadcast row->C-layout via shfl ----
    if (growB) {
      f32x4 av;
#pragma unroll
      for (int r = 0; r < 4; ++r) av[r] = __shfl(alphaB, quad * 4 + r);
#pragma unroll
      for (int t = 0; t < 8; ++t) {
        oB[t][0] *= av[0]; oB[t][1] *= av[1]; oB[t][2] *= av[2]; oB[t][3] *= av[3];
      }
    }
    if (growA) {
      f32x4 av;
#pragma unroll
      for (int r = 0; r < 4; ++r) av[r] = __shfl(alphaA, quad * 4 + r);
#pragma unroll
      for (int t = 0; t < 8; ++t) {
        oA[t][0] *= av[0]; oA[t][1] *= av[1]; oA[t][2] *= av[2]; oA[t][3] *= av[3];
      }
    }

    // ---- PV, V-frags shared by both tiles (pi-permuted layout matches pk order) ----
#pragma unroll
    for (int t = 0; t < 8; ++t) {
      const bf16x8 vf = *(const bf16x8*)&Vs[((t * 16 + n16) * 32 + quad * 8) ^ ((n16 & 3) << 3)];
      oB[t] = __builtin_amdgcn_mfma_f32_16x16x32_bf16(pkB.v, vf, oB[t], 0, 0, 0);
      if (actA) oA[t] = __builtin_amdgcn_mfma_f32_16x16x32_bf16(pkA.v, vf, oA[t], 0, 0, 0);
    }

    __syncthreads();      // all waves done reading this chunk's K/V tiles
    if (c + 1 < nchB) {
      *(u16x8*)&Ks[kdst0] = ka;
      *(u16x8*)&Ks[kdst1] = kb;
      *(u16x8*)&Vs[vdst0] = va;
      *(u16x8*)&Vs[vdst1] = vb;
    }
    __syncthreads();      // next chunk's tiles visible to all waves
  }

  // ---- epilogue: normalize (l via shfl), store bf16 (both tiles) ----
  {
    unsigned short* obB = O + ((size_t)(b * T_ + q0B)) * (H_ * HD_) + h * HD_;
    unsigned short* obA = O + ((size_t)(b * T_ + q0A)) * (H_ * HD_) + h * HD_;
#pragma unroll
    for (int r = 0; r < 4; ++r) {
      const float liB = 1.0f / __shfl(lB, quad * 4 + r);
      const float liA = 1.0f / __shfl(lA, quad * 4 + r);
#pragma unroll
      for (int t = 0; t < 8; ++t) {
        obB[(size_t)(quad * 4 + r) * (H_ * HD_) + t * 16 + n16] = f2bu(oB[t][r] * liB);
        obA[(size_t)(quad * 4 + r) * (H_ * HD_) + t * 16 + n16] = f2bu(oA[t][r] * liA);
      }
    }
  }
}

extern "C" void kernel_launch(void* const* d_in, const int* in_sizes, int n_in,
                              void* d_out, int out_size, void* d_ws, size_t ws_size,
                              hipStream_t stream) {
  const float* x  = (const float*)d_in[0];
  const float* fc = (const float*)d_in[1];
  const float* fs = (const float*)d_in[2];
  const float* Wq = (const float*)d_in[3];
  const float* Wk = (const float*)d_in[4];
  const float* Wv = (const float*)d_in[5];
  const float* Wo = (const float*)d_in[6];

  // Outputs (f32), concatenated: y | present_k | present_v
  float* yout = (float*)d_out;                          // [B,T,D]
  float* kout = yout + (size_t)B_ * T_ * D_;            // [B,KV,T,HD]
  float* vout = kout + (size_t)B_ * KV_ * T_ * HD_;     // [B,KV,T,HD]
  unsigned short* Qbf = (unsigned short*)yout;          // bf16 Q staging in yout region

  // workspace (bf16, 44 MB): xb/Abf (aliased) | Wqt | Wkvt | Wot | Kbf | VbfT
  unsigned short* xb   = (unsigned short*)d_ws;                    // [BT, D]
  unsigned short* Abf  = xb;                                       // alias: xb dead after gemm128<1>
  unsigned short* Wqt  = xb   + (size_t)BT_ * D_;                  // [2048, 2048]
  unsigned short* Wkvt = Wqt  + (size_t)D_ * D_;                   // [1024, 2048] (contiguous after Wqt)
  unsigned short* Wot  = Wkvt + (size_t)1024 * D_;                 // [2048, 2048]
  unsigned short* Kbf  = Wot  + (size_t)D_ * D_;                   // [B,KV,T,HD]
  unsigned short* VbfT = Kbf  + (size_t)B_ * KV_ * T_ * HD_;       // [B*KV, HD, T] (pi-permuted)

  dim3 blk(256);

  // input conversions
  cvt_bf16<<<dim3((BT_ * D_) / 1024), blk, 0, stream>>>(x, xb);
  t32_all<<<dim3(D_ / 32, D_ / 32, 4), blk, 0, stream>>>(Wq, Wk, Wv, Wo, Wqt, Wkvt, Wot);

  // fused QKV projection + RoPE (128^2 counted-vmcnt, 768 blocks; Bt = Wqt||Wkvt contiguous)
  gemm128<1><<<dim3(NPROJ_ / 128, BT_ / 128), blk, 0, stream>>>(
      xb, Wqt, nullptr, Qbf, kout, vout, Kbf, fc, fs, NPROJ_);

  // V^T bf16 mirror (pi-permuted)
  v_transpose<<<dim3(T_ / 32, HD_ / 32, B_ * KV_), blk, 0, stream>>>(vout, VbfT);

  // flash attention v5: 512 equal-work paired blocks, 4 waves each
  attn_flash<<<dim3(64, B_ * KV_), blk, 0, stream>>>(Qbf, Kbf, VbfT, Abf);

  // output projection (128^2 counted-vmcnt, 512 blocks); overwrites Qbf staging with y
  gemm128<0><<<dim3(D_ / 128, BT_ / 128), blk, 0, stream>>>(
      Abf, Wot, yout, nullptr, nullptr, nullptr, nullptr, nullptr, nullptr, D_);
}